// Round 8
// baseline (120.122 us; speedup 1.0000x reference)
//
#include <hip/hip_runtime.h>

// SSIM, fused separable, column-sliding register ring + wave-private LDS row
// staging via global_load_lds DMA. v6 = v5 with STRIP_H 64->32.
// R7 analysis: VALU per-SIMD ~16%, LDS ~30%, HBM 6% -> latency-bound at
// 12 waves/CU grid cap. This round doubles the block pool (1536 blocks,
// 6 blocks/CU, 24 waves/CU dispatched) for 2x latency-hiding TLP at the
// cost of +13.6% warmup steps.

#define IMG_H 512
#define IMG_W 512
#define N_PLANES 48
#define KW 11
#define RING 12
#define BLOCK 256
#define WAVE_COLS 64
#define STRIP_H 32
#define BLOCKS_X (IMG_W / (WAVE_COLS * 4))            // 2
#define BLOCKS_Y (IMG_H / STRIP_H)                    // 16
#define NBLK (N_PLANES * BLOCKS_X * BLOCKS_Y)         // 1536
#define SLOT 160                                      // floats per buf per img
#define C1_CONST 1.0e-4f
#define C2_CONST 9.0e-4f

typedef const __attribute__((address_space(1))) void GV;
typedef __attribute__((address_space(3))) void LV;

__device__ __forceinline__ void dma16(const float* g, float* l) {
  __builtin_amdgcn_global_load_lds((GV*)g, (LV*)l, 16, 0, 0);
}

__device__ __forceinline__ float bcastf(float x) {
  return __uint_as_float(__builtin_amdgcn_readfirstlane(__float_as_uint(x)));
}

#define TAPX(E, AV, BV) { const float w_ = Wp[(E)]; \
    const float t1_ = w_ * (AV); const float t2_ = w_ * (BV); \
    m1_ += t1_; m2_ += t2_; \
    q12_ += t1_ * (BV); qs_ += t1_ * (AV); qs_ += t2_ * (BV); }

#define EMT(K, QQ) { const float w_ = wkr[(K)]; \
    vm1_ += w_ * rm1[(QQ)]; vm2_ += w_ * rm2[(QQ)]; \
    vqs_ += w_ * rqs[(QQ)]; vq12_ += w_ * rq12[(QQ)]; }

// One pipeline step, Q = step % 12 (compile-time). Buffer parity Q&1.
// 1) issue 2 DMAs for row gr+1 into buf (Q+1)&1   (stay in flight)
// 2) s_waitcnt vmcnt(2): previous step's DMAs (buf Q&1) now complete
// 3) ds_read window from buf Q&1, H-pass -> ring slot Q
// 4) emit output row gr-5 from ring (if EMIT)
#define STEPQ(Q, EMIT) { \
  { const int nr_ = gr + 1; \
    const int nrc_ = nr_ < 0 ? 0 : (nr_ > IMG_H - 1 ? IMG_H - 1 : nr_); \
    if (lane < 20) { \
      const size_t ro_ = (size_t)nrc_ * IMG_W + c0; \
      dma16(p1 + ro_, sl1 + (((Q) + 1) & 1) * SLOT); \
      dma16(p2 + ro_, sl2 + (((Q) + 1) & 1) * SLOT); \
    } } \
  asm volatile("s_waitcnt vmcnt(2)" ::: "memory"); \
  __builtin_amdgcn_sched_barrier(0); \
  if (gr >= 0 && gr < IMG_H) { \
    const float* sb1_ = sl1 + ((Q) & 1) * SLOT; \
    const float* sb2_ = sl2 + ((Q) & 1) * SLOT; \
    float m1_ = 0.f, m2_ = 0.f, qs_ = 0.f, q12_ = 0.f; \
    { const float4 A0 = *(const float4*)(sb1_ + a); \
      const float4 A1 = *(const float4*)(sb1_ + a + 4); \
      const float4 B0 = *(const float4*)(sb2_ + a); \
      const float4 B1 = *(const float4*)(sb2_ + a + 4); \
      TAPX(0, A0.x, B0.x) TAPX(1, A0.y, B0.y) TAPX(2, A0.z, B0.z) \
      TAPX(3, A0.w, B0.w) TAPX(4, A1.x, B1.x) TAPX(5, A1.y, B1.y) \
      TAPX(6, A1.z, B1.z) TAPX(7, A1.w, B1.w) } \
    { const float4 A2 = *(const float4*)(sb1_ + a + 8); \
      const float2 A3 = *(const float2*)(sb1_ + a + 12); \
      const float4 B2 = *(const float4*)(sb2_ + a + 8); \
      const float2 B3 = *(const float2*)(sb2_ + a + 12); \
      TAPX(8, A2.x, B2.x)  TAPX(9, A2.y, B2.y)  TAPX(10, A2.z, B2.z) \
      TAPX(11, A2.w, B2.w) TAPX(12, A3.x, B3.x) TAPX(13, A3.y, B3.y) } \
    rm1[(Q)] = m1_; rm2[(Q)] = m2_; rqs[(Q)] = qs_; rq12[(Q)] = q12_; \
  } else { \
    rm1[(Q)] = 0.f; rm2[(Q)] = 0.f; rqs[(Q)] = 0.f; rq12[(Q)] = 0.f; } \
  if (EMIT) { \
    float vm1_ = 0.f, vm2_ = 0.f, vqs_ = 0.f, vq12_ = 0.f; \
    EMT(0, ((Q)+2)%RING)  EMT(1, ((Q)+3)%RING)  EMT(2, ((Q)+4)%RING) \
    EMT(3, ((Q)+5)%RING)  EMT(4, ((Q)+6)%RING)  EMT(5, ((Q)+7)%RING) \
    EMT(6, ((Q)+8)%RING)  EMT(7, ((Q)+9)%RING)  EMT(8, ((Q)+10)%RING) \
    EMT(9, ((Q)+11)%RING) EMT(10, (Q)) \
    const float mu11_ = vm1_ * vm1_; \
    const float mu22_ = vm2_ * vm2_; \
    const float mu12_ = vm1_ * vm2_; \
    const float musum_ = mu11_ + mu22_; \
    const float sigs_  = vqs_  - musum_; \
    const float sig12_ = vq12_ - mu12_; \
    const float num_ = (2.f * mu12_ + C1_CONST) * (2.f * sig12_ + C2_CONST); \
    const float den_ = (musum_ + C1_CONST) * (sigs_ + C2_CONST); \
    acc += num_ * __builtin_amdgcn_rcpf(den_); \
  } \
  gr++; \
}

__global__ __launch_bounds__(BLOCK) void ssim_strip_kernel(
    const float* __restrict__ img1,
    const float* __restrict__ img2,
    const float* __restrict__ kern2d,
    float* __restrict__ partial)
{
  // Wave-private double-buffered row slices: [wave][buf][img][80]. 10 KiB.
  __shared__ __align__(16) float slice[4][2][2][80];
  __shared__ float wk_lds[KW];
  __shared__ float wave_sums[BLOCK / 64];

  const int tid  = threadIdx.x;
  const int wid  = tid >> 6;
  const int lane = tid & 63;

  // 1D kernel = row sums of the normalized 2D kernel (== normalized 1D Gaussian).
  if (tid < KW) {
    float s = 0.f;
    #pragma unroll
    for (int j = 0; j < KW; ++j) s += kern2d[tid * KW + j];
    wk_lds[tid] = s;
  }
  __syncthreads();

  // V-pass weights, wave-uniform (SGPRs).
  float wkr[KW];
  #pragma unroll
  for (int k = 0; k < KW; ++k) wkr[k] = bcastf(wk_lds[k]);

  const int bid   = blockIdx.x;
  const int plane = bid / (BLOCKS_X * BLOCKS_Y);
  const int srem  = bid % (BLOCKS_X * BLOCKS_Y);
  const int y0    = (srem / BLOCKS_X) * STRIP_H;
  const int x0b   = (srem % BLOCKS_X) * (WAVE_COLS * 4);
  const float* __restrict__ p1 = img1 + (size_t)plane * IMG_H * IMG_W;
  const float* __restrict__ p2 = img2 + (size_t)plane * IMG_H * IMG_W;

  const int x0w   = x0b + wid * WAVE_COLS;   // wave's first column
  const int gx    = x0w + lane;              // this thread's output column
  const int wbase = x0w - 8;                 // slice float 0 <-> global col wbase

  // Lane's window: slice floats [a, a+15]; taps at e in [r, r+10].
  const int a = (lane + 3) & ~3;
  const int r = (lane + 3) & 3;

  float Wp[14];
  #pragma unroll
  for (int e = 0; e < 14; ++e) {
    const int k   = e - r;
    const int col = wbase + a + e;
    Wp[e] = (k >= 0 && k <= 10 && col >= 0 && col < IMG_W) ? wk_lds[k] : 0.f;
  }

  // DMA source column for lanes 0..19 (16B chunk -> slice floats 4l..4l+3).
  // wbase % 4 == 0, IMG_W % 4 == 0: each 4-float group is entirely in- or
  // out-of-image; clamped addresses only affect fully-OOB groups (Wp-zeroed).
  const int c0r = wbase + 4 * lane;
  const int c0  = c0r < 0 ? 0 : (c0r > IMG_W - 4 ? IMG_W - 4 : c0r);

  float* sl1 = &slice[wid][0][0][0];   // img1; buf b at +b*SLOT
  float* sl2 = &slice[wid][0][1][0];   // img2; buf b at +b*SLOT

  float rm1[RING], rm2[RING], rqs[RING], rq12[RING];
  float acc = 0.f;
  int gr = y0 - 5;

  // Prologue: DMA row y0-5 (clamped; contents unused if invalid) into buf 0.
  {
    const int r0 = gr < 0 ? 0 : gr;
    if (lane < 20) {
      const size_t ro = (size_t)r0 * IMG_W + c0;
      dma16(p1 + ro, sl1);
      dma16(p2 + ro, sl2);
    }
  }

  // 42 steps: 10 warmup, 32 emitting. Q = step % 12 (compile-time).
  STEPQ(0, 0) STEPQ(1, 0) STEPQ(2, 0) STEPQ(3, 0) STEPQ(4, 0)
  STEPQ(5, 0) STEPQ(6, 0) STEPQ(7, 0) STEPQ(8, 0) STEPQ(9, 0)
  STEPQ(10, 1) STEPQ(11, 1)
  #pragma unroll 1
  for (int it = 0; it < 2; ++it) {
    STEPQ(0, 1) STEPQ(1, 1) STEPQ(2, 1) STEPQ(3, 1) STEPQ(4, 1)
    STEPQ(5, 1) STEPQ(6, 1) STEPQ(7, 1) STEPQ(8, 1) STEPQ(9, 1)
    STEPQ(10, 1) STEPQ(11, 1)
  }
  STEPQ(0, 1) STEPQ(1, 1) STEPQ(2, 1) STEPQ(3, 1) STEPQ(4, 1) STEPQ(5, 1)

  // Block reduction.
  #pragma unroll
  for (int off = 32; off > 0; off >>= 1)
    acc += __shfl_down(acc, off, 64);
  if ((tid & 63) == 0) wave_sums[tid >> 6] = acc;
  __syncthreads();
  if (tid == 0)
    partial[bid] = wave_sums[0] + wave_sums[1] + wave_sums[2] + wave_sums[3];
}

__global__ __launch_bounds__(256) void ssim_reduce_kernel(
    const float* __restrict__ partial, float* __restrict__ out)
{
  const int tid = threadIdx.x;
  double acc = 0.0;
  for (int i = tid; i < NBLK; i += 256) acc += (double)partial[i];
  #pragma unroll
  for (int off = 32; off > 0; off >>= 1)
    acc += __shfl_down(acc, off, 64);
  __shared__ double wsums[4];
  if ((tid & 63) == 0) wsums[tid >> 6] = acc;
  __syncthreads();
  if (tid == 0) {
    const double total = wsums[0] + wsums[1] + wsums[2] + wsums[3];
    const double inv_n = 1.0 / ((double)N_PLANES * IMG_H * IMG_W);
    out[0] = (float)(total * inv_n);
  }
}

extern "C" void kernel_launch(void* const* d_in, const int* in_sizes, int n_in,
                              void* d_out, int out_size, void* d_ws, size_t ws_size,
                              hipStream_t stream)
{
  const float* img1 = (const float*)d_in[0];
  const float* img2 = (const float*)d_in[1];
  const float* kern = (const float*)d_in[2];
  float* out = (float*)d_out;
  float* partial = (float*)d_ws;   // NBLK floats = 6 KiB

  ssim_strip_kernel<<<NBLK, BLOCK, 0, stream>>>(img1, img2, kern, partial);
  ssim_reduce_kernel<<<1, 256, 0, stream>>>(partial, out);
}

// Round 9
// 105.026 us; speedup vs baseline: 1.1437x; 1.1437x over previous
//
#include <hip/hip_runtime.h>

// SSIM, fused separable, column-sliding register ring + wave-private LDS row
// staging via global_load_lds DMA. v7.
// vs R7/R8: ONE DMA instruction per row per wave (40 active lanes: lanes
// 0-19 source img1, lanes 20-39 source img2; LDS dest = base + lane*16 lands
// img2 at the slice's second half automatically), triple-buffered slices with
// 2-step prefetch depth: step Q issues row gr+2 into buf (Q+2)%3 and
// s_waitcnt vmcnt(2) waits only for row gr, issued ~2 full steps (~2500 cyc)
// earlier. STRIP_H=64 (R8's 32 was a regression: +23.8% warmup not paid back).

#define IMG_H 512
#define IMG_W 512
#define N_PLANES 48
#define KW 11
#define RING 12
#define BLOCK 256
#define WAVE_COLS 64
#define STRIP_H 64
#define BLOCKS_X (IMG_W / (WAVE_COLS * 4))            // 2
#define BLOCKS_Y (IMG_H / STRIP_H)                    // 8
#define NBLK (N_PLANES * BLOCKS_X * BLOCKS_Y)         // 768
#define SLOTF 160                                     // floats per buf: img1 80 | img2 80
#define C1_CONST 1.0e-4f
#define C2_CONST 9.0e-4f

typedef const __attribute__((address_space(1))) void GV;
typedef __attribute__((address_space(3))) void LV;

__device__ __forceinline__ void dma16(const float* g, float* l) {
  __builtin_amdgcn_global_load_lds((GV*)g, (LV*)l, 16, 0, 0);
}

__device__ __forceinline__ float bcastf(float x) {
  return __uint_as_float(__builtin_amdgcn_readfirstlane(__float_as_uint(x)));
}

#define TAPX(E, AV, BV) { const float w_ = Wp[(E)]; \
    const float t1_ = w_ * (AV); const float t2_ = w_ * (BV); \
    m1_ += t1_; m2_ += t2_; \
    q12_ += t1_ * (BV); qs_ += t1_ * (AV); qs_ += t2_ * (BV); }

#define EMT(K, QQ) { const float w_ = wkr[(K)]; \
    vm1_ += w_ * rm1[(QQ)]; vm2_ += w_ * rm2[(QQ)]; \
    vqs_ += w_ * rqs[(QQ)]; vq12_ += w_ * rq12[(QQ)]; }

// One pipeline step, Q = step % 12 (compile-time). Buffer = Q%3.
// 1) issue 1 DMA for row gr+2 into buf (Q+2)%3    (2-step prefetch depth)
// 2) s_waitcnt vmcnt(2): row gr's DMA (issued 2 steps ago) now complete
// 3) ds_read window from buf Q%3, H-pass -> ring slot Q
// 4) emit output row gr-5 from ring (if EMIT)
// Race-free buffer reuse: buf (Q+2)%3 was last ds_read in step Q-1, and all
// those reads completed (lgkmcnt-waited before their FMA consumers) before
// this step's DMA issues in program order.
#define STEPQ(Q, EMIT) { \
  { const int nr_ = gr + 2; \
    const int nrc_ = nr_ < 0 ? 0 : (nr_ > IMG_H - 1 ? IMG_H - 1 : nr_); \
    if (lane < 40) \
      dma16(srcbase + (size_t)nrc_ * IMG_W, slw + (((Q) + 2) % 3) * SLOTF); \
  } \
  asm volatile("s_waitcnt vmcnt(2)" ::: "memory"); \
  __builtin_amdgcn_sched_barrier(0); \
  if (gr >= 0 && gr < IMG_H) { \
    const float* sb1_ = slw + ((Q) % 3) * SLOTF; \
    const float* sb2_ = sb1_ + 80; \
    float m1_ = 0.f, m2_ = 0.f, qs_ = 0.f, q12_ = 0.f; \
    { const float4 A0 = *(const float4*)(sb1_ + a); \
      const float4 A1 = *(const float4*)(sb1_ + a + 4); \
      const float4 B0 = *(const float4*)(sb2_ + a); \
      const float4 B1 = *(const float4*)(sb2_ + a + 4); \
      TAPX(0, A0.x, B0.x) TAPX(1, A0.y, B0.y) TAPX(2, A0.z, B0.z) \
      TAPX(3, A0.w, B0.w) TAPX(4, A1.x, B1.x) TAPX(5, A1.y, B1.y) \
      TAPX(6, A1.z, B1.z) TAPX(7, A1.w, B1.w) } \
    { const float4 A2 = *(const float4*)(sb1_ + a + 8); \
      const float2 A3 = *(const float2*)(sb1_ + a + 12); \
      const float4 B2 = *(const float4*)(sb2_ + a + 8); \
      const float2 B3 = *(const float2*)(sb2_ + a + 12); \
      TAPX(8, A2.x, B2.x)  TAPX(9, A2.y, B2.y)  TAPX(10, A2.z, B2.z) \
      TAPX(11, A2.w, B2.w) TAPX(12, A3.x, B3.x) TAPX(13, A3.y, B3.y) } \
    rm1[(Q)] = m1_; rm2[(Q)] = m2_; rqs[(Q)] = qs_; rq12[(Q)] = q12_; \
  } else { \
    rm1[(Q)] = 0.f; rm2[(Q)] = 0.f; rqs[(Q)] = 0.f; rq12[(Q)] = 0.f; } \
  if (EMIT) { \
    float vm1_ = 0.f, vm2_ = 0.f, vqs_ = 0.f, vq12_ = 0.f; \
    EMT(0, ((Q)+2)%RING)  EMT(1, ((Q)+3)%RING)  EMT(2, ((Q)+4)%RING) \
    EMT(3, ((Q)+5)%RING)  EMT(4, ((Q)+6)%RING)  EMT(5, ((Q)+7)%RING) \
    EMT(6, ((Q)+8)%RING)  EMT(7, ((Q)+9)%RING)  EMT(8, ((Q)+10)%RING) \
    EMT(9, ((Q)+11)%RING) EMT(10, (Q)) \
    const float mu11_ = vm1_ * vm1_; \
    const float mu22_ = vm2_ * vm2_; \
    const float mu12_ = vm1_ * vm2_; \
    const float musum_ = mu11_ + mu22_; \
    const float sigs_  = vqs_  - musum_; \
    const float sig12_ = vq12_ - mu12_; \
    const float num_ = (2.f * mu12_ + C1_CONST) * (2.f * sig12_ + C2_CONST); \
    const float den_ = (musum_ + C1_CONST) * (sigs_ + C2_CONST); \
    acc += num_ * __builtin_amdgcn_rcpf(den_); \
  } \
  gr++; \
}

__global__ __launch_bounds__(BLOCK) void ssim_strip_kernel(
    const float* __restrict__ img1,
    const float* __restrict__ img2,
    const float* __restrict__ kern2d,
    float* __restrict__ partial)
{
  // Wave-private triple-buffered row slices: [wave][buf][img1 80|img2 80].
  __shared__ __align__(16) float slice[4][3][SLOTF];   // 7680 B
  __shared__ float wk_lds[KW];
  __shared__ float wave_sums[BLOCK / 64];

  const int tid  = threadIdx.x;
  const int wid  = tid >> 6;
  const int lane = tid & 63;

  // 1D kernel = row sums of the normalized 2D kernel (== normalized 1D Gaussian).
  if (tid < KW) {
    float s = 0.f;
    #pragma unroll
    for (int j = 0; j < KW; ++j) s += kern2d[tid * KW + j];
    wk_lds[tid] = s;
  }
  __syncthreads();

  // V-pass weights, wave-uniform (SGPRs).
  float wkr[KW];
  #pragma unroll
  for (int k = 0; k < KW; ++k) wkr[k] = bcastf(wk_lds[k]);

  const int bid   = blockIdx.x;
  const int plane = bid / (BLOCKS_X * BLOCKS_Y);
  const int srem  = bid % (BLOCKS_X * BLOCKS_Y);
  const int y0    = (srem / BLOCKS_X) * STRIP_H;
  const int x0b   = (srem % BLOCKS_X) * (WAVE_COLS * 4);
  const float* __restrict__ p1 = img1 + (size_t)plane * IMG_H * IMG_W;
  const float* __restrict__ p2 = img2 + (size_t)plane * IMG_H * IMG_W;

  const int x0w   = x0b + wid * WAVE_COLS;   // wave's first column
  const int gx    = x0w + lane;              // this thread's output column
  const int wbase = x0w - 8;                 // slice float 0 <-> global col wbase

  // Lane's window: slice floats [a, a+15]; taps at e in [r, r+10].
  const int a = (lane + 3) & ~3;
  const int r = (lane + 3) & 3;

  float Wp[14];
  #pragma unroll
  for (int e = 0; e < 14; ++e) {
    const int k   = e - r;
    const int col = wbase + a + e;
    Wp[e] = (k >= 0 && k <= 10 && col >= 0 && col < IMG_W) ? wk_lds[k] : 0.f;
  }

  // DMA source: lanes 0..19 cover img1 floats 4l..4l+3, lanes 20..39 cover
  // img2 floats 4(l-20)..4(l-20)+3 (landing at slice floats 80..159 via the
  // HW's base + lane*16 LDS addressing). wbase % 4 == 0, IMG_W % 4 == 0:
  // each 4-float group is entirely in- or out-of-image; clamped addresses
  // only affect fully-OOB groups, whose taps Wp zeroes.
  const int li  = lane < 20 ? lane : lane - 20;
  const int c0r = wbase + 4 * li;
  const int c0  = c0r < 0 ? 0 : (c0r > IMG_W - 4 ? IMG_W - 4 : c0r);
  const float* srcbase = (lane < 20 ? p1 : p2) + c0;

  float* slw = &slice[wid][0][0];

  float rm1[RING], rm2[RING], rqs[RING], rq12[RING];
  float acc = 0.f;
  int gr = y0 - 5;

  // Prologue: issue rows gr (buf 0) and gr+1 (buf 1), oldest first.
  {
    const int r0 = gr     < 0 ? 0 : gr;
    const int r1 = gr + 1 < 0 ? 0 : gr + 1;
    if (lane < 40) {
      dma16(srcbase + (size_t)r0 * IMG_W, slw);
      dma16(srcbase + (size_t)r1 * IMG_W, slw + SLOTF);
    }
  }

  // 74 steps: 10 warmup, 64 emitting. Q = step % 12 (compile-time).
  STEPQ(0, 0) STEPQ(1, 0) STEPQ(2, 0) STEPQ(3, 0) STEPQ(4, 0)
  STEPQ(5, 0) STEPQ(6, 0) STEPQ(7, 0) STEPQ(8, 0) STEPQ(9, 0)
  STEPQ(10, 1) STEPQ(11, 1)
  #pragma unroll 1
  for (int it = 0; it < 5; ++it) {
    STEPQ(0, 1) STEPQ(1, 1) STEPQ(2, 1) STEPQ(3, 1) STEPQ(4, 1)
    STEPQ(5, 1) STEPQ(6, 1) STEPQ(7, 1) STEPQ(8, 1) STEPQ(9, 1)
    STEPQ(10, 1) STEPQ(11, 1)
  }
  STEPQ(0, 1) STEPQ(1, 1)

  // Block reduction.
  #pragma unroll
  for (int off = 32; off > 0; off >>= 1)
    acc += __shfl_down(acc, off, 64);
  if ((tid & 63) == 0) wave_sums[tid >> 6] = acc;
  __syncthreads();
  if (tid == 0)
    partial[bid] = wave_sums[0] + wave_sums[1] + wave_sums[2] + wave_sums[3];
}

__global__ __launch_bounds__(256) void ssim_reduce_kernel(
    const float* __restrict__ partial, float* __restrict__ out)
{
  const int tid = threadIdx.x;
  double acc = 0.0;
  for (int i = tid; i < NBLK; i += 256) acc += (double)partial[i];
  #pragma unroll
  for (int off = 32; off > 0; off >>= 1)
    acc += __shfl_down(acc, off, 64);
  __shared__ double wsums[4];
  if ((tid & 63) == 0) wsums[tid >> 6] = acc;
  __syncthreads();
  if (tid == 0) {
    const double total = wsums[0] + wsums[1] + wsums[2] + wsums[3];
    const double inv_n = 1.0 / ((double)N_PLANES * IMG_H * IMG_W);
    out[0] = (float)(total * inv_n);
  }
}

extern "C" void kernel_launch(void* const* d_in, const int* in_sizes, int n_in,
                              void* d_out, int out_size, void* d_ws, size_t ws_size,
                              hipStream_t stream)
{
  const float* img1 = (const float*)d_in[0];
  const float* img2 = (const float*)d_in[1];
  const float* kern = (const float*)d_in[2];
  float* out = (float*)d_out;
  float* partial = (float*)d_ws;   // NBLK floats = 3 KiB

  ssim_strip_kernel<<<NBLK, BLOCK, 0, stream>>>(img1, img2, kern, partial);
  ssim_reduce_kernel<<<1, 256, 0, stream>>>(partial, out);
}

// Round 10
// 103.472 us; speedup vs baseline: 1.1609x; 1.0150x over previous
//
#include <hip/hip_runtime.h>

// SSIM, fused separable, column-sliding register ring + wave-private LDS
// staging via global_load_lds DMA. v8: TWO ROWS PER PIPELINE STEP.
// Cross-round invariant (R4/R7/R9): ~1140 cyc per step per SIMD-slot
// regardless of step internals -> fixed per-step overhead window dominates.
// This round halves the step count (74 -> 37): each step DMAs a 2-row pair
// (triple pair-buffer, vmcnt(4) = pair issued 2 steps earlier), runs 2
// H-passes into ring slots 2p,2p+1, and emits 2 output rows. Ring=12,
// phase period 6; buf = p%3; all indices compile-time.

#define IMG_H 512
#define IMG_W 512
#define N_PLANES 48
#define KW 11
#define BLOCK 256
#define WAVE_COLS 64
#define STRIP_H 64
#define BLOCKS_X (IMG_W / (WAVE_COLS * 4))            // 2
#define BLOCKS_Y (IMG_H / STRIP_H)                    // 8
#define NBLK (N_PLANES * BLOCKS_X * BLOCKS_Y)         // 768
#define PAIRF 320          // floats per pair-buf: row0[img1 80|img2 80] row1[...]
#define C1_CONST 1.0e-4f
#define C2_CONST 9.0e-4f

typedef const __attribute__((address_space(1))) void GV;
typedef __attribute__((address_space(3))) void LV;

__device__ __forceinline__ void dma16(const float* g, float* l) {
  __builtin_amdgcn_global_load_lds((GV*)g, (LV*)l, 16, 0, 0);
}

__device__ __forceinline__ float bcastf(float x) {
  return __uint_as_float(__builtin_amdgcn_readfirstlane(__float_as_uint(x)));
}

#define TAPX(E, AV, BV) { const float w_ = Wp[(E)]; \
    const float t1_ = w_ * (AV); const float t2_ = w_ * (BV); \
    m1_ += t1_; m2_ += t2_; \
    q12_ += t1_ * (BV); qs_ += t1_ * (AV); qs_ += t2_ * (BV); }

// H-pass of one row from slice base BP (img1 at +0, img2 at +80) into ring
// slot SLOT; zeros if ROW outside the image (zero-pad convolution).
#define HPASS(ROW, SLOT, BP) { \
  if ((ROW) >= 0 && (ROW) < IMG_H) { \
    const float* s1_ = (BP); const float* s2_ = (BP) + 80; \
    float m1_ = 0.f, m2_ = 0.f, qs_ = 0.f, q12_ = 0.f; \
    { const float4 A0 = *(const float4*)(s1_ + a); \
      const float4 A1 = *(const float4*)(s1_ + a + 4); \
      const float4 B0 = *(const float4*)(s2_ + a); \
      const float4 B1 = *(const float4*)(s2_ + a + 4); \
      TAPX(0, A0.x, B0.x) TAPX(1, A0.y, B0.y) TAPX(2, A0.z, B0.z) \
      TAPX(3, A0.w, B0.w) TAPX(4, A1.x, B1.x) TAPX(5, A1.y, B1.y) \
      TAPX(6, A1.z, B1.z) TAPX(7, A1.w, B1.w) } \
    { const float4 A2 = *(const float4*)(s1_ + a + 8); \
      const float2 A3 = *(const float2*)(s1_ + a + 12); \
      const float4 B2 = *(const float4*)(s2_ + a + 8); \
      const float2 B3 = *(const float2*)(s2_ + a + 12); \
      TAPX(8, A2.x, B2.x)  TAPX(9, A2.y, B2.y)  TAPX(10, A2.z, B2.z) \
      TAPX(11, A2.w, B2.w) TAPX(12, A3.x, B3.x) TAPX(13, A3.y, B3.y) } \
    rm1[(SLOT)] = m1_; rm2[(SLOT)] = m2_; \
    rqs[(SLOT)] = qs_; rq12[(SLOT)] = q12_; \
  } else { \
    rm1[(SLOT)] = 0.f; rm2[(SLOT)] = 0.f; \
    rqs[(SLOT)] = 0.f; rq12[(SLOT)] = 0.f; } }

#define EMT(K, QQ) { const float w_ = wkr[(K)]; \
    vm1_ += w_ * rm1[(QQ)]; vm2_ += w_ * rm2[(QQ)]; \
    vqs_ += w_ * rqs[(QQ)]; vq12_ += w_ * rq12[(QQ)]; }

// V-pass + SSIM for one output row whose tap-k ring slot is (OFF+K)%12.
#define EMITQ(OFF) { \
  float vm1_ = 0.f, vm2_ = 0.f, vqs_ = 0.f, vq12_ = 0.f; \
  EMT(0, ((OFF)+0)%12)  EMT(1, ((OFF)+1)%12)  EMT(2, ((OFF)+2)%12) \
  EMT(3, ((OFF)+3)%12)  EMT(4, ((OFF)+4)%12)  EMT(5, ((OFF)+5)%12) \
  EMT(6, ((OFF)+6)%12)  EMT(7, ((OFF)+7)%12)  EMT(8, ((OFF)+8)%12) \
  EMT(9, ((OFF)+9)%12)  EMT(10, ((OFF)+10)%12) \
  const float mu11_ = vm1_ * vm1_; \
  const float mu22_ = vm2_ * vm2_; \
  const float mu12_ = vm1_ * vm2_; \
  const float musum_ = mu11_ + mu22_; \
  const float sigs_  = vqs_  - musum_; \
  const float sig12_ = vq12_ - mu12_; \
  const float num_ = (2.f * mu12_ + C1_CONST) * (2.f * sig12_ + C2_CONST); \
  const float den_ = (musum_ + C1_CONST) * (sigs_ + C2_CONST); \
  acc += num_ * __builtin_amdgcn_rcpf(den_); }

// One 2-row step, phase P = step % 6 (compile-time).
// Rows processed: (gr, gr+1); ring slots (2P)%12, (2P+1)%12; buf P%3.
// Issues the pair for step+2 (rows gr+4, gr+5) into buf (P+2)%3, then
// vmcnt(4) waits only for THIS step's pair (issued 2 steps ago).
// Emits output rows with tap bases (2P+2)%12 and (2P+3)%12.
#define STEP2(P, EMIT) { \
  { const int na_ = gr+4 < 0 ? 0 : (gr+4 > IMG_H-1 ? IMG_H-1 : gr+4); \
    const int nb_ = gr+5 < 0 ? 0 : (gr+5 > IMG_H-1 ? IMG_H-1 : gr+5); \
    if (lane < 40) { \
      float* d_ = slw + (((P)+2)%3) * PAIRF; \
      dma16(srcbase + (size_t)na_ * IMG_W, d_); \
      dma16(srcbase + (size_t)nb_ * IMG_W, d_ + 160); } } \
  asm volatile("s_waitcnt vmcnt(4)" ::: "memory"); \
  __builtin_amdgcn_sched_barrier(0); \
  { const float* bp_ = slw + ((P)%3) * PAIRF; \
    HPASS(gr,     (2*(P))%12,     bp_) \
    HPASS(gr + 1, (2*(P)+1)%12,   bp_ + 160) } \
  if (EMIT) { EMITQ((2*(P)+2)%12) EMITQ((2*(P)+3)%12) } \
  gr += 2; }

__global__ __launch_bounds__(BLOCK) void ssim_strip_kernel(
    const float* __restrict__ img1,
    const float* __restrict__ img2,
    const float* __restrict__ kern2d,
    float* __restrict__ partial)
{
  // Wave-private triple pair-buffers: [wave][buf3][row2][img2][80]. 15,360 B.
  __shared__ __align__(16) float slice[4][3][2][2][80];
  __shared__ float wk_lds[KW];
  __shared__ float wave_sums[BLOCK / 64];

  const int tid  = threadIdx.x;
  const int wid  = tid >> 6;
  const int lane = tid & 63;

  // 1D kernel = row sums of the normalized 2D kernel (== normalized 1D Gaussian).
  if (tid < KW) {
    float s = 0.f;
    #pragma unroll
    for (int j = 0; j < KW; ++j) s += kern2d[tid * KW + j];
    wk_lds[tid] = s;
  }
  __syncthreads();

  // V-pass weights, wave-uniform (SGPRs).
  float wkr[KW];
  #pragma unroll
  for (int k = 0; k < KW; ++k) wkr[k] = bcastf(wk_lds[k]);

  const int bid   = blockIdx.x;
  const int plane = bid / (BLOCKS_X * BLOCKS_Y);
  const int srem  = bid % (BLOCKS_X * BLOCKS_Y);
  const int y0    = (srem / BLOCKS_X) * STRIP_H;
  const int x0b   = (srem % BLOCKS_X) * (WAVE_COLS * 4);
  const float* __restrict__ p1 = img1 + (size_t)plane * IMG_H * IMG_W;
  const float* __restrict__ p2 = img2 + (size_t)plane * IMG_H * IMG_W;

  const int x0w   = x0b + wid * WAVE_COLS;   // wave's first column
  const int gx    = x0w + lane;              // this thread's output column
  const int wbase = x0w - 8;                 // slice float 0 <-> global col wbase

  // Lane's window: slice floats [a, a+13]; taps at e in [r, r+10].
  const int a = (lane + 3) & ~3;
  const int r = (lane + 3) & 3;

  float Wp[14];
  #pragma unroll
  for (int e = 0; e < 14; ++e) {
    const int k   = e - r;
    const int col = wbase + a + e;
    Wp[e] = (k >= 0 && k <= 10 && col >= 0 && col < IMG_W) ? wk_lds[k] : 0.f;
  }

  // DMA source: lanes 0..19 cover img1 floats 4l..4l+3 of the 80-float span,
  // lanes 20..39 cover img2 (landing at +80 floats via dest = base+lane*16).
  // wbase % 4 == 0, IMG_W % 4 == 0: each 4-float group entirely in- or
  // out-of-image; clamped addresses only affect fully-OOB groups (Wp-zeroed).
  const int li  = lane < 20 ? lane : lane - 20;
  const int c0r = wbase + 4 * li;
  const int c0  = c0r < 0 ? 0 : (c0r > IMG_W - 4 ? IMG_W - 4 : c0r);
  const float* srcbase = (lane < 20 ? p1 : p2) + c0;

  float* slw = &slice[wid][0][0][0][0];

  float rm1[12], rm2[12], rqs[12], rq12[12];
  float acc = 0.f;
  int gr = y0 - 5;

  // Prologue: stage pairs for steps 0 (buf 0) and 1 (buf 1), oldest first.
  {
    const int q0 = gr     < 0 ? 0 : gr;
    const int q1 = gr + 1 < 0 ? 0 : gr + 1;
    const int q2 = gr + 2 < 0 ? 0 : gr + 2;
    const int q3 = gr + 3 < 0 ? 0 : gr + 3;
    if (lane < 40) {
      dma16(srcbase + (size_t)q0 * IMG_W, slw);
      dma16(srcbase + (size_t)q1 * IMG_W, slw + 160);
      dma16(srcbase + (size_t)q2 * IMG_W, slw + PAIRF);
      dma16(srcbase + (size_t)q3 * IMG_W, slw + PAIRF + 160);
    }
  }

  // 37 steps x 2 rows = 74 rows (y0-5 .. y0+68); steps 0-4 warm up the ring,
  // steps 5-36 emit 2 output rows each (64 rows). Phase = step % 6.
  STEP2(0, 0) STEP2(1, 0) STEP2(2, 0) STEP2(3, 0) STEP2(4, 0)
  STEP2(5, 1)
  #pragma unroll 1
  for (int it = 0; it < 5; ++it) {
    STEP2(0, 1) STEP2(1, 1) STEP2(2, 1) STEP2(3, 1) STEP2(4, 1) STEP2(5, 1)
  }
  STEP2(0, 1)

  // Block reduction.
  #pragma unroll
  for (int off = 32; off > 0; off >>= 1)
    acc += __shfl_down(acc, off, 64);
  if ((tid & 63) == 0) wave_sums[tid >> 6] = acc;
  __syncthreads();
  if (tid == 0)
    partial[bid] = wave_sums[0] + wave_sums[1] + wave_sums[2] + wave_sums[3];
}

__global__ __launch_bounds__(256) void ssim_reduce_kernel(
    const float* __restrict__ partial, float* __restrict__ out)
{
  const int tid = threadIdx.x;
  double acc = 0.0;
  for (int i = tid; i < NBLK; i += 256) acc += (double)partial[i];
  #pragma unroll
  for (int off = 32; off > 0; off >>= 1)
    acc += __shfl_down(acc, off, 64);
  __shared__ double wsums[4];
  if ((tid & 63) == 0) wsums[tid >> 6] = acc;
  __syncthreads();
  if (tid == 0) {
    const double total = wsums[0] + wsums[1] + wsums[2] + wsums[3];
    const double inv_n = 1.0 / ((double)N_PLANES * IMG_H * IMG_W);
    out[0] = (float)(total * inv_n);
  }
}

extern "C" void kernel_launch(void* const* d_in, const int* in_sizes, int n_in,
                              void* d_out, int out_size, void* d_ws, size_t ws_size,
                              hipStream_t stream)
{
  const float* img1 = (const float*)d_in[0];
  const float* img2 = (const float*)d_in[1];
  const float* kern = (const float*)d_in[2];
  float* out = (float*)d_out;
  float* partial = (float*)d_ws;   // NBLK floats = 3 KiB

  ssim_strip_kernel<<<NBLK, BLOCK, 0, stream>>>(img1, img2, kern, partial);
  ssim_reduce_kernel<<<1, 256, 0, stream>>>(partial, out);
}